// Round 10
// baseline (599.284 us; speedup 1.0000x reference)
//
#include <hip/hip_runtime.h>
#include <hip/hip_fp16.h>
#include <cstddef>

// StackLSTM: T=64, B=128, H=256, L=2.  ops∈{0,1} => stack never pops:
// top-of-stack = h(last push step), maintained by gated update.
//
// Round-10: r9 geometry (1024 WGs, 4b x 8 h-cols, 48 weight VGPRs/thread,
// tagged dataflow) + software pipeline: iteration t computes L1(t) AND
// L0(t+1), publishes h1(t)+h0(t+1), then ONE combined poll phase. 65 exchange
// rounds instead of 128. Co-resident WGs now from different batch groups
// (bg = blk>>5) so their dataflow stalls are uncorrelated and overlap.
#define TT 64
#define BB 128
#define HH 256
#define G4 1024
#define BLK 256
#define NBG 32
#define NHG 32

// ws float-slot offsets
#define OFF_XG     0u          // [64 t][32 hg][128 b][32 lc] fp32 = 8,388,608
#define OFF_WTIH0  8388608u    // [256][1024] fp32 W_ih[0]^T (for xg) = 262,144
#define OFF_HX0    8650752u    // u64 [2 par][32 bg][4 b][128 k2] = 65,536 floats
#define OFF_HX1    8716288u    // same
// total 8,781,824 floats = 35.1 MB

__device__ __forceinline__ float sigf(float x) { return 1.0f / (1.0f + expf(-x)); }

typedef _Float16 h2v __attribute__((ext_vector_type(2)));

__device__ __forceinline__ float dot2acc(unsigned w, unsigned h, float acc) {
#if __has_builtin(__builtin_amdgcn_fdot2)
  return __builtin_amdgcn_fdot2(__builtin_bit_cast(h2v, w),
                                __builtin_bit_cast(h2v, h), acc, false);
#else
  __half2 wv = *(__half2*)&w, hv = *(__half2*)&h;
  float2 wf = __half22float2(wv), hf = __half22float2(hv);
  return fmaf(wf.x, hf.x, fmaf(wf.y, hf.y, acc));
#endif
}

__device__ __forceinline__ unsigned packh2(float e, float o) {
  return (unsigned)__half_as_ushort(__float2half(e)) |
         ((unsigned)__half_as_ushort(__float2half(o)) << 16);
}

// ---------------------------------------------------------------------------
// transpose W_ih[0] [1024][256] -> [256][1024] fp32 (for xg_kernel)
// ---------------------------------------------------------------------------
__global__ void transpose1(const float* __restrict__ W_ih, float* __restrict__ ws) {
  __shared__ float tile[32][33];
  float* dst = ws + OFF_WTIH0;
  const int g0 = blockIdx.x * 32, k0 = blockIdx.y * 32;
  const int tx = threadIdx.x, ty = threadIdx.y;
#pragma unroll
  for (int i = 0; i < 32; i += 8)
    tile[ty + i][tx] = W_ih[(size_t)(g0 + ty + i) * HH + k0 + tx];
  __syncthreads();
#pragma unroll
  for (int i = 0; i < 32; i += 8)
    dst[(size_t)(k0 + ty + i) * G4 + g0 + tx] = tile[tx][ty + i];
}

// ---------------------------------------------------------------------------
// Xg[t][hg][b][lc] = b_ih0[g] + x[t,b,:] @ W_ih0[g,:]   (fp32, exact)
// hg = (g>>3)&31, lc = (g>>8)*8 + (g&7)
// ---------------------------------------------------------------------------
__global__ void xg_kernel(const float* __restrict__ x,
                          const float* __restrict__ b_ih,
                          float* __restrict__ ws) {
  const float* __restrict__ WTih0 = ws + OFF_WTIH0;
  float* __restrict__ Xg = ws + OFF_XG;
  const int r0 = blockIdx.x * 16;
  const int g = blockIdx.y * 256 + threadIdx.x;
  __shared__ float xs[16][HH];
  for (int i = threadIdx.x; i < 16 * HH; i += 256)
    xs[i >> 8][i & 255] = x[(size_t)(r0 + (i >> 8)) * HH + (i & 255)];
  __syncthreads();
  float acc[16];
  const float bias = b_ih[g];
#pragma unroll
  for (int r = 0; r < 16; ++r) acc[r] = bias;
  for (int k = 0; k < HH; ++k) {
    const float w = WTih0[(size_t)k * G4 + g];
#pragma unroll
    for (int r = 0; r < 16; ++r) acc[r] = fmaf(xs[r][k], w, acc[r]);
  }
  const int hg = (g >> 3) & 31;
  const int lc = ((g >> 8) << 3) | (g & 7);
#pragma unroll
  for (int r = 0; r < 16; ++r) {
    const int rr = r0 + r;
    const int t = rr >> 7, b = rr & 127;
    Xg[(((size_t)t * NHG + hg) * 128 + b) * 32 + lc] = acc[r];
  }
}

// ---------------------------------------------------------------------------
// Sequential recurrence: pipelined tagged dataflow, 48 weight regs/thread.
// Thread (cc = tid>>3, kq = tid&7): col cc, k2 slice
// {s*32 + kq*4 + i : s in 0..3, i in 0..3} (bank-conflict-free b128 reads).
// ---------------------------------------------------------------------------
__global__ void __launch_bounds__(BLK, 4)
seq10(const float* __restrict__ W_ih,
      const float* __restrict__ W_hh,
      const float* __restrict__ b_ih,
      const float* __restrict__ b_hh,
      const int* __restrict__ ops,
      float* __restrict__ ws,
      float* __restrict__ out) {
  const int bg = blockIdx.x >> 5;     // batch group (4 b) — co-residents differ
  const int hg = blockIdx.x & 31;     // 0..31 h-col group
  const int tid = threadIdx.x;
  const int kq = tid & 7;
  const int cc = tid >> 3;            // 0..31: local gate col

  __shared__ unsigned hp0[512];       // [4 b][128 k2] f16-pair gated h0
  __shared__ unsigned hp1[512];
  __shared__ unsigned h0c[512];       // raw h0(t), layer-1 input
  __shared__ float gat0[128];         // gates0(t+1) partial [4 b][32 lc]
  __shared__ float gat1[128];         // gates1(t)   partial
  __shared__ float xgb[128];          // Xg(t+1) [4 b][32 lc]
  __shared__ int opsA[TT * 4];        // [t][b]

  // ---- prologue: weights -> VGPRs (f16 pairs, strided-k layout) ----
  unsigned wr0[16], wr1[16], wr2[16];
  const int g = ((cc >> 3) << 8) + hg * 8 + (cc & 7);
  {
    const float* s0 = W_hh;                       // W_hh[0]
    const float* s1 = W_ih + (size_t)G4 * HH;     // W_ih[1]
    const float* s2 = W_hh + (size_t)G4 * HH;     // W_hh[1]
#pragma unroll
    for (int s = 0; s < 4; ++s)
#pragma unroll
      for (int i = 0; i < 4; ++i) {
        const int k2 = s * 32 + kq * 4 + i;
        const float* p0 = s0 + (size_t)g * HH + 2 * k2;
        const float* p1 = s1 + (size_t)g * HH + 2 * k2;
        const float* p2 = s2 + (size_t)g * HH + 2 * k2;
        wr0[s * 4 + i] = packh2(p0[0], p0[1]);
        wr1[s * 4 + i] = packh2(p1[0], p1[1]);
        wr2[s * 4 + i] = packh2(p2[0], p2[1]);
      }
  }
  const float bias0 = b_hh[g];                     // b_ih0 folded into Xg
  const float bias1 = b_ih[G4 + g] + b_hh[G4 + g];
  for (int i = tid; i < TT * 4; i += BLK)
    opsA[i] = ops[(i >> 2) * BB + bg * 4 + (i & 3)];
  for (int i = tid; i < 512; i += BLK) { hp0[i] = 0u; hp1[i] = 0u; }

  unsigned long long* __restrict__ Hx0 = (unsigned long long*)(ws + OFF_HX0);
  unsigned long long* __restrict__ Hx1 = (unsigned long long*)(ws + OFF_HX1);
  float cp0 = 0.f;                    // layer-0 cell state (wave0 lanes 0..31)
  float cp1 = 0.f;                    // layer-1 cell state (wave1 lanes 0..31)

  // ---- pipeline prologue: step-0 layer-0 (hp0 = 0 -> dots are zero) ----
  if (kq == 0) {
#pragma unroll
    for (int b = 0; b < 4; ++b) gat0[b * 32 + cc] = bias0;
  }
  if (tid < 128)
    xgb[tid] = ws[OFF_XG + (((size_t)0 * NHG + hg) * 128 + bg * 4 + (tid >> 5)) * 32 +
                  (tid & 31)];
  __syncthreads();
  if (tid < 32) {
    const int b = tid >> 3, r = tid & 7;
    const float* gt = &gat0[b * 32];
    const float* xg = &xgb[b * 32];
    const float ig = gt[r] + xg[r],           fg = gt[8 + r] + xg[8 + r];
    const float gg = gt[16 + r] + xg[16 + r], og = gt[24 + r] + xg[24 + r];
    const float c = sigf(ig) * tanhf(gg) + sigf(fg) * cp0;  // cp0 = 0
    const float h = sigf(og) * tanhf(c);
    if (opsA[b]) cp0 = c;
    const float ho = __shfl_xor(h, 1, 64);
    if (!(r & 1)) {
      const unsigned long long v = 1ull | ((unsigned long long)packh2(h, ho) << 32);
      __hip_atomic_store(Hx0 + ((size_t)0 * NBG + bg) * 512 + b * 128 + hg * 4 + (r >> 1),
                         v, __ATOMIC_RELAXED, __HIP_MEMORY_SCOPE_AGENT);
    }
  }
  // merge h0(0)
#pragma unroll
  for (int i = 0; i < 2; ++i) {
    const int idx = tid + i * 256;
    const int b = idx >> 7, k2 = idx & 127;
    const unsigned long long* s0 = Hx0 + ((size_t)0 * NBG + bg) * 512;
    unsigned long long v;
    int spins = 0;
    for (;;) {
      v = __hip_atomic_load(s0 + idx, __ATOMIC_RELAXED, __HIP_MEMORY_SCOPE_AGENT);
      if ((unsigned)v == 1u) break;
      if (++spins > (1 << 18)) break;  // fail loudly instead of hanging
      __builtin_amdgcn_s_sleep(1);
    }
    const unsigned pay = (unsigned)(v >> 32);
    h0c[b * 128 + k2] = pay;
    if (opsA[b]) hp0[b * 128 + k2] = pay;
  }
  __syncthreads();

  // ---- main loop: iteration t does L1(t) and L0(t+1) ----
  for (int t = 0; t < TT; ++t) {
    const bool last = (t == TT - 1);

    // Xg(t+1) early load
    float xgv = 0.f;
    if (!last && tid < 128)
      xgv = ws[OFF_XG + (((size_t)(t + 1) * NHG + hg) * 128 + bg * 4 + (tid >> 5)) * 32 +
               (tid & 31)];

    // ---- L1(t) dots: wr1 . h0c + wr2 . hp1 ----
    float a1[4];
#pragma unroll
    for (int b = 0; b < 4; ++b) {
      float a = 0.f;
#pragma unroll
      for (int s = 0; s < 4; ++s) {
        const uint4 hc = *(const uint4*)&h0c[b * 128 + s * 32 + kq * 4];
        const uint4 hq = *(const uint4*)&hp1[b * 128 + s * 32 + kq * 4];
        a = dot2acc(wr1[s * 4 + 0], hc.x, a);
        a = dot2acc(wr1[s * 4 + 1], hc.y, a);
        a = dot2acc(wr1[s * 4 + 2], hc.z, a);
        a = dot2acc(wr1[s * 4 + 3], hc.w, a);
        a = dot2acc(wr2[s * 4 + 0], hq.x, a);
        a = dot2acc(wr2[s * 4 + 1], hq.y, a);
        a = dot2acc(wr2[s * 4 + 2], hq.z, a);
        a = dot2acc(wr2[s * 4 + 3], hq.w, a);
      }
      a1[b] = a;
    }
    // ---- L0(t+1) dots: wr0 . hp0 ----
    float a0[4];
#pragma unroll
    for (int b = 0; b < 4; ++b) {
      float a = 0.f;
#pragma unroll
      for (int s = 0; s < 4; ++s) {
        const uint4 hx = *(const uint4*)&hp0[b * 128 + s * 32 + kq * 4];
        a = dot2acc(wr0[s * 4 + 0], hx.x, a);
        a = dot2acc(wr0[s * 4 + 1], hx.y, a);
        a = dot2acc(wr0[s * 4 + 2], hx.z, a);
        a = dot2acc(wr0[s * 4 + 3], hx.w, a);
      }
      a0[b] = a;
    }
#pragma unroll
    for (int m = 1; m <= 4; m <<= 1)
#pragma unroll
      for (int b = 0; b < 4; ++b) {
        a1[b] += __shfl_xor(a1[b], m, 64);
        a0[b] += __shfl_xor(a0[b], m, 64);
      }
    if (kq == 0) {
#pragma unroll
      for (int b = 0; b < 4; ++b) {
        gat1[b * 32 + cc] = a1[b] + bias1;
        gat0[b * 32 + cc] = a0[b] + bias0;
      }
    }
    if (!last && tid < 128) xgb[tid] = xgv;
    __syncthreads();

    // ---- cells: cell0(t+1) on wave0 lanes 0..31; cell1(t) on wave1 ----
    if (tid < 32) {
      if (!last) {
        const int b = tid >> 3, r = tid & 7;
        const float* gt = &gat0[b * 32];
        const float* xg = &xgb[b * 32];
        const float ig = gt[r] + xg[r],           fg = gt[8 + r] + xg[8 + r];
        const float gg = gt[16 + r] + xg[16 + r], og = gt[24 + r] + xg[24 + r];
        const float c = sigf(fg) * cp0 + sigf(ig) * tanhf(gg);
        const float h = sigf(og) * tanhf(c);
        if (opsA[(t + 1) * 4 + b]) cp0 = c;
        const float ho = __shfl_xor(h, 1, 64);
        if (!(r & 1)) {
          const unsigned long long v =
              (unsigned long long)(unsigned)(t + 2) |
              ((unsigned long long)packh2(h, ho) << 32);
          __hip_atomic_store(
              Hx0 + ((size_t)((t + 1) & 1) * NBG + bg) * 512 + b * 128 + hg * 4 + (r >> 1),
              v, __ATOMIC_RELAXED, __HIP_MEMORY_SCOPE_AGENT);
        }
      }
    } else if (tid >= 64 && tid < 96) {
      const int lane = tid - 64;
      const int b = lane >> 3, r = lane & 7;
      const float* gt = &gat1[b * 32];
      const float ig = gt[r],      fg = gt[8 + r];
      const float gg = gt[16 + r], og = gt[24 + r];
      const float c = sigf(fg) * cp1 + sigf(ig) * tanhf(gg);
      const float h = sigf(og) * tanhf(c);
      if (opsA[t * 4 + b]) cp1 = c;
      out[((size_t)t * BB + bg * 4 + b) * HH + hg * 8 + r] = h;
      const float ho = __shfl_xor(h, 1, 64);
      if (!(r & 1)) {
        const unsigned long long v =
            (unsigned long long)(unsigned)(t + 1) |
            ((unsigned long long)packh2(h, ho) << 32);
        __hip_atomic_store(
            Hx1 + ((size_t)(t & 1) * NBG + bg) * 512 + b * 128 + hg * 4 + (r >> 1),
            v, __ATOMIC_RELAXED, __HIP_MEMORY_SCOPE_AGENT);
      }
    }

    // ---- combined merge: poll h1(t) and h0(t+1) ----
#pragma unroll
    for (int i = 0; i < 2; ++i) {
      const int idx = tid + i * 256;
      const int b = idx >> 7, k2 = idx & 127;
      {
        const unsigned long long* s1 = Hx1 + ((size_t)(t & 1) * NBG + bg) * 512;
        const unsigned tagB = (unsigned)(t + 1);
        unsigned long long v;
        int spins = 0;
        for (;;) {
          v = __hip_atomic_load(s1 + idx, __ATOMIC_RELAXED, __HIP_MEMORY_SCOPE_AGENT);
          if ((unsigned)v == tagB) break;
          if (++spins > (1 << 18)) break;
          __builtin_amdgcn_s_sleep(1);
        }
        if (opsA[t * 4 + b]) hp1[b * 128 + k2] = (unsigned)(v >> 32);
      }
      if (!last) {
        const unsigned long long* s0 =
            Hx0 + ((size_t)((t + 1) & 1) * NBG + bg) * 512;
        const unsigned tagA = (unsigned)(t + 2);
        unsigned long long v;
        int spins = 0;
        for (;;) {
          v = __hip_atomic_load(s0 + idx, __ATOMIC_RELAXED, __HIP_MEMORY_SCOPE_AGENT);
          if ((unsigned)v == tagA) break;
          if (++spins > (1 << 18)) break;
          __builtin_amdgcn_s_sleep(1);
        }
        const unsigned pay = (unsigned)(v >> 32);
        h0c[b * 128 + k2] = pay;
        if (opsA[(t + 1) * 4 + b]) hp0[b * 128 + k2] = pay;
      }
    }
    __syncthreads();
  }
}

// ---------------------------------------------------------------------------
extern "C" void kernel_launch(void* const* d_in, const int* in_sizes, int n_in,
                              void* d_out, int out_size, void* d_ws, size_t ws_size,
                              hipStream_t stream) {
  const float* x    = (const float*)d_in[0];
  const int*   ops  = (const int*)d_in[1];
  const float* W_ih = (const float*)d_in[2];
  const float* W_hh = (const float*)d_in[3];
  const float* b_ih = (const float*)d_in[4];
  const float* b_hh = (const float*)d_in[5];
  float* out = (float*)d_out;
  float* ws  = (float*)d_ws;

  transpose1<<<dim3(32, 8), dim3(32, 8), 0, stream>>>(W_ih, ws);
  xg_kernel<<<dim3(512, 4), 256, 0, stream>>>(x, b_ih, ws);
  seq10<<<1024, BLK, 0, stream>>>(W_ih, W_hh, b_ih, b_hh, ops, ws, out);
}